// Round 16
// baseline (243.039 us; speedup 1.0000x reference)
//
#include <hip/hip_runtime.h>
#include <hip/hip_bf16.h>

typedef __attribute__((ext_vector_type(8))) short short8;
typedef __attribute__((ext_vector_type(4))) float f32x4;

#define MFMA16(a,b,c) __builtin_amdgcn_mfma_f32_16x16x32_bf16((a),(b),(c),0,0,0)

constexpr int BHn = 32;     // B*NH
constexpr int Tn  = 2048;
constexpr int Nn  = 512;
constexpr int Dn  = 128;
constexpr int CHn = 128;    // chunk length
constexpr int NCH = Tn / CHn;   // 16

static __device__ __forceinline__ unsigned short f2b(float x){
  __hip_bfloat16 h = __float2bfloat16(x);
  return *reinterpret_cast<unsigned short*>(&h);
}

// ---------------- Kernel 1: RoPE(Q) -> bf16 row-major QR ----------------
__global__ __launch_bounds__(256) void rope_k(const float* __restrict__ Q,
                                              const float* __restrict__ freqs,
                                              unsigned short* __restrict__ QR){
  int gid = blockIdx.x * 256 + threadIdx.x;
  int np  = gid & 255;
  int t   = gid >> 8;
  float tf = (float)t;
  float f1 = freqs[np], f2 = freqs[np + 256];
  float s1, c1, s2, c2;
  sincosf(tf * f1, &s1, &c1);
  sincosf(tf * f2, &s2, &c2);
  size_t off = (size_t)t * Nn + np;
  for (int bh = 0; bh < BHn; ++bh){
    size_t base = (size_t)bh * Tn * Nn + off;
    float q1 = Q[base], q2 = Q[base + 256];
    QR[base]       = f2b(q1 * c1 - q2 * s1);
    QR[base + 256] = f2b(q2 * c2 + q1 * s2);
  }
}

// ---------------- fragment loaders ----------------
// swizzled loader (LDS or global swizzled image): col ^= (row&7)<<3 (bits 3-5 only)
__device__ __forceinline__ short8 ldfrag(const unsigned short* buf, int rowbase, int k0, int ld, int lane){
  int row = rowbase + (lane & 15);
  int col = (k0 + ((lane >> 4) << 3)) ^ ((row & 7) << 3);
  return *reinterpret_cast<const short8*>(buf + row * ld + col);
}
// global row-major frag: lane reads R[rowbase+(lane&15)][k0+(lane>>4)*8 ..+8]
__device__ __forceinline__ short8 gfrag(const unsigned short* Qc, int rowbase, int k0, int lane){
  return *reinterpret_cast<const short8*>(
      Qc + (size_t)(rowbase + (lane & 15)) * Nn + k0 + ((lane >> 4) << 3));
}

// ---------------- Kernel 2 (parallel, LDS-staged): full lower-tri P~ image ---------------
// grid 512 = bh + 32*cc; block 512 (8 waves). Stage the whole 128x512 chunk in LDS once
// (128 KB), then wave w owns row-group ti=w: product tiles tj<w, diag-masked tile tj=w,
// zero tiles tj>w. Frag streams come from LDS (round-7 lesson: dense streams need LDS).
__global__ __launch_bounds__(512) void pd_k2(const unsigned short* __restrict__ QR,
                                             const float* __restrict__ gammap,
                                             unsigned short* __restrict__ Pt){
  __shared__ __align__(16) unsigned short Rs[128 * 512];   // 128 KB
  __shared__ float gpow[129];
  const int tid = threadIdx.x, w = tid >> 6, lane = tid & 63;
  const int bh = blockIdx.x & 31, cc = blockIdx.x >> 5;
  if (tid < 129) gpow[tid] = powf(gammap[0], (float)tid);
  const unsigned short* Qc = QR + (size_t)bh * Tn * Nn + (size_t)(cc * CHn) * Nn;
  // stage: 8192 uint4 = 128 rows x 64 uint4; 16 per thread, coalesced within a row
  #pragma unroll
  for (int i = 0; i < 16; ++i){
    int p  = tid + i * 512;
    int dt = p >> 6, n0 = (p & 63) << 3;
    uint4 a = *reinterpret_cast<const uint4*>(Qc + (size_t)dt * Nn + n0);
    *reinterpret_cast<uint4*>(&Rs[dt * 512 + (n0 ^ ((dt & 7) << 3))]) = a;
  }
  __syncthreads();

  f32x4 acc[8];
  #pragma unroll
  for (int t = 0; t < 8; ++t) acc[t] = {0.f, 0.f, 0.f, 0.f};
  for (int kb = 0; kb < 16; ++kb){
    int k0 = kb * 32;
    short8 fa = ldfrag(Rs, w * 16, k0, 512, lane);
    #pragma unroll
    for (int tj = 0; tj < 8; ++tj) if (tj <= w){
      short8 fb = ldfrag(Rs, tj * 16, k0, 512, lane);
      acc[tj] = MFMA16(fa, fb, acc[tj]);
    }
  }

  unsigned short* Pq = Pt + (size_t)(bh * NCH + cc) * (CHn * CHn);
  #pragma unroll
  for (int tj = 0; tj < 8; ++tj){
    int jg = tj * 16 + (lane & 15);
    int i0 = w * 16 + ((lane >> 4) << 2);
    #pragma unroll
    for (int r = 0; r < 4; ++r){
      int ig = i0 + r;
      float v;
      if (tj < w)       v = acc[tj][r] * gpow[ig];              // full product tile
      else if (tj == w) v = (jg < ig) ? acc[tj][r] * gpow[ig] : 0.f;  // diag-masked
      else              v = 0.f;                                 // causal zero
      Pq[ig * CHn + (jg ^ ((ig & 7) << 3))] = f2b(v);
    }
  }
}

// ---------------- Kernel 3: scan (round-12 lattn_main, verbatim) ----------------
__global__ __launch_bounds__(512, 1) void lattn_main(
    const unsigned short* __restrict__ QR,
    const unsigned short* __restrict__ Pt,
    const float* __restrict__ V,
    const float* __restrict__ S_prev,
    const float* __restrict__ gammap,
    float* __restrict__ Out,
    float* __restrict__ Sfin)
{
  __shared__ __align__(16) unsigned short SbTs[16 * 512];
  __shared__ __align__(16) unsigned short VTs[2][16 * 128];
  __shared__ float gpow[129], gpinv[129];

  const int tid  = threadIdx.x;
  const int w    = tid >> 6;
  const int lane = tid & 63;
  const int bh   = blockIdx.x & 31;
  const int dch  = blockIdx.x >> 5;
  const int d0   = dch * 16;
  const float g  = gammap[0];

  const unsigned short* QRbh = QR + (size_t)bh * Tn * Nn;
  const unsigned short* Ptbh = Pt + (size_t)bh * NCH * (CHn * CHn);
  const float* Vbh = V + (size_t)bh * Tn * Dn;

  if (tid < 129){
    gpow[tid]  = powf(g,  (float)tid);
    gpinv[tid] = powf(g, -(float)tid);
  }

  const int snt = (w < 4) ? 2 : 6;
  const int sb  = (w < 4) ? w * 2 : 8 + (w - 4) * 6;
  f32x4 st[6];
  #pragma unroll
  for (int j = 0; j < 6; ++j) if (j < snt){
    int n = (sb + j) * 16 + (lane & 15);
    st[j] = *reinterpret_cast<const f32x4*>(
        S_prev + (size_t)bh * Nn * Dn + (size_t)n * Dn + d0 + ((lane >> 4) << 2));
  }
  __syncthreads();
  const float g128 = gpow[128];

  #pragma unroll
  for (int j = 0; j < 6; ++j) if (j < snt){
    int n  = (sb + j) * 16 + (lane & 15);
    int dl = (lane >> 4) << 2;
    #pragma unroll
    for (int r = 0; r < 4; ++r){
      int d = dl + r;
      SbTs[d * 512 + (n ^ ((d & 7) << 3))] = f2b(st[j][r]);
    }
  }
  {
    int dtv = tid >> 2, dp0 = (tid & 3) << 2;
    f32x4 v4 = *reinterpret_cast<const f32x4*>(Vbh + (size_t)dtv * Dn + d0 + dp0);
    float sc = gpinv[dtv];
    #pragma unroll
    for (int r = 0; r < 4; ++r){
      int d = dp0 + r;
      VTs[0][d * 128 + (dtv ^ ((d & 7) << 3))] = f2b(v4[r] * sc);
    }
  }
  __syncthreads();

  for (int c = 0; c < NCH; ++c){
    const int t0 = c * CHn;
    const int vb = c & 1;
    const bool pf = (c + 1 < NCH);
    const unsigned short* Qc = QRbh + (size_t)t0 * Nn;

    f32x4 va4 = {0.f, 0.f, 0.f, 0.f};
    const int dtv_ = tid >> 2, dp0_ = (tid & 3) << 2;
    if (pf)
      va4 = *reinterpret_cast<const f32x4*>(Vbh + (size_t)(t0 + CHn + dtv_) * Dn + d0 + dp0_);

    if (w < 4){
      const int it0 = w, it1 = w + 4;
      f32x4 o0 = {0.f,0.f,0.f,0.f}, o1 = o0;
      for (int kb = 0; kb < 16; ++kb){
        int k0 = kb * 32;
        short8 fs = ldfrag(SbTs, 0, k0, 512, lane);
        short8 fa = gfrag(Qc, it0 * 16, k0, lane);
        short8 fb = gfrag(Qc, it1 * 16, k0, lane);
        o0 = MFMA16(fs, fa, o0);
        o1 = MFMA16(fs, fb, o1);
      }
      float g0 = gpow[it0 * 16 + (lane & 15)];
      float g1 = gpow[it1 * 16 + (lane & 15)];
      #pragma unroll
      for (int r = 0; r < 4; ++r){ o0[r] *= g0; o1[r] *= g1; }
      const unsigned short* Pq = Ptbh + (size_t)c * (CHn * CHn);
      #pragma unroll
      for (int ks = 0; ks < 4; ++ks){
        short8 av = ldfrag(VTs[vb], 0, ks * 32, 128, lane);
        if (ks < 2){
          short8 b0 = ldfrag(Pq, it0 * 16, ks * 32, CHn, lane);
          o0 = MFMA16(av, b0, o0);
        }
        short8 b1 = ldfrag(Pq, it1 * 16, ks * 32, CHn, lane);
        o1 = MFMA16(av, b1, o1);
      }
      int ti0 = t0 + it0 * 16 + (lane & 15);
      int ti1 = t0 + it1 * 16 + (lane & 15);
      *reinterpret_cast<f32x4*>(
          Out + (size_t)bh * Tn * Dn + (size_t)ti0 * Dn + d0 + ((lane >> 4) << 2)) = o0;
      *reinterpret_cast<f32x4*>(
          Out + (size_t)bh * Tn * Dn + (size_t)ti1 * Dn + d0 + ((lane >> 4) << 2)) = o1;
    }
    #pragma unroll
    for (int ks = 0; ks < 4; ++ks){
      short8 av = ldfrag(VTs[vb], 0, ks * 32, 128, lane);
      #pragma unroll
      for (int j = 0; j < 6; ++j) if (j < snt){
        int n = (sb + j) * 16 + (lane & 15);
        const unsigned short* col = Qc + (size_t)(ks * 32 + ((lane >> 4) << 3)) * Nn + n;
        short8 bn;
        #pragma unroll
        for (int e = 0; e < 8; ++e) bn[e] = (short)col[(size_t)e * Nn];
        st[j] = MFMA16(av, bn, st[j]);
      }
    }
    #pragma unroll
    for (int j = 0; j < 6; ++j) if (j < snt)
      #pragma unroll
      for (int r = 0; r < 4; ++r) st[j][r] *= g128;
    __syncthreads();

    #pragma unroll
    for (int j = 0; j < 6; ++j) if (j < snt){
      int n  = (sb + j) * 16 + (lane & 15);
      int dl = (lane >> 4) << 2;
      #pragma unroll
      for (int r = 0; r < 4; ++r){
        int d = dl + r;
        SbTs[d * 512 + (n ^ ((d & 7) << 3))] = f2b(st[j][r]);
      }
    }
    if (pf){
      float sc = gpinv[dtv_];
      #pragma unroll
      for (int r = 0; r < 4; ++r){
        int d = dp0_ + r;
        VTs[vb ^ 1][d * 128 + (dtv_ ^ ((d & 7) << 3))] = f2b(va4[r] * sc);
      }
    }
    __syncthreads();
  }

  #pragma unroll
  for (int j = 0; j < 6; ++j) if (j < snt){
    int n = (sb + j) * 16 + (lane & 15);
    *reinterpret_cast<f32x4*>(
        Sfin + (size_t)bh * Nn * Dn + (size_t)n * Dn + d0 + ((lane >> 4) << 2)) = st[j];
  }
}

extern "C" void kernel_launch(void* const* d_in, const int* in_sizes, int n_in,
                              void* d_out, int out_size, void* d_ws, size_t ws_size,
                              hipStream_t stream){
  const float* Q      = (const float*)d_in[0];
  const float* V      = (const float*)d_in[1];
  const float* S_prev = (const float*)d_in[2];
  const float* freqs  = (const float*)d_in[3];
  const float* gamma  = (const float*)d_in[4];
  float* Out  = (float*)d_out;
  float* Sfin = Out + (size_t)BHn * Tn * Dn;

  unsigned short* QR = (unsigned short*)d_ws;                 // 64 MiB bf16
  unsigned short* Pt = QR + (size_t)BHn * Tn * Nn;            // +16 MiB P~ images

  rope_k<<<2048, 256, 0, stream>>>(Q, freqs, QR);
  pd_k2<<<512, 512, 0, stream>>>(QR, gamma, Pt);
  lattn_main<<<256, 512, 0, stream>>>(QR, Pt, V, S_prev, gamma, Out, Sfin);
}